// Round 2
// baseline (200.891 us; speedup 1.0000x reference)
//
#include <hip/hip_runtime.h>
#include <stdint.h>

// Problem constants: B=32, L=8192, C=64, M=64. All I/O fp32.
#define L_     8192
#define NB     32
#define NC     64
#define SPLITK 16
#define CHUNK  (L_ / SPLITK)   // 512
#define SXPAD  520             // LDS row stride (bf16 elems): 512 + 8 pad

// d_out (64 MiB fp32) doubles as scratch for k0..k2; k3 overwrites all of it
// and reads none of it (TF bridged through the dead wr input buffer by k2b).
#define BF_OFF  0            // Bf table:    128 x 8192 bf16 = 2 MiB
#define XF_OFF  (2u  << 20)  // XF partials: 16 x 32 x 8192 fp32 = 16 MiB
#define XR_OFF  (18u << 20)  // XF reduced:  32 x 8192 fp32 = 1 MiB   [c][j] layout
#define TF_OFF  (19u << 20)  // TF staging:  32 x 64 x 192 bf16 = 768 KiB

typedef __bf16 bf16x8 __attribute__((ext_vector_type(8)));
typedef float  f32x4  __attribute__((ext_vector_type(4)));

__device__ __forceinline__ unsigned short f2bf(float f) {
  union { float f; unsigned int i; } v; v.f = f;
  unsigned int r = v.i + 0x7fffu + ((v.i >> 16) & 1u);  // RNE (cold paths)
  return (unsigned short)(r >> 16);
}
__device__ __forceinline__ f32x4 mfma16(bf16x8 a, bf16x8 b, f32x4 c) {
  return __builtin_amdgcn_mfma_f32_16x16x32_bf16(a, b, c, 0, 0, 0);
}

// ---------------------------------------------------------------------------
// k0: forward DFT basis Bf[j][l] (bf16): j=2k: a_k cos(2pi k l/L), j=2k+1:
// -a_k sin. a_k = (k==0?1:2)/L folds the irfft normalization forward.
// 8 elems/thread, uint4 stores.
// ---------------------------------------------------------------------------
__global__ __launch_bounds__(256) void k0_bf(unsigned short* __restrict__ Bf) {
  const int e0 = (blockIdx.x * 256 + threadIdx.x) * 8;
  const int j = e0 >> 13, l0 = e0 & 8191, k = j >> 1;
  const float W0 = 6.283185307179586f / 8192.0f;
  const float a = (k == 0 ? 1.0f : 2.0f) * (1.0f / 8192.0f);
  uint32_t w[4];
  #pragma unroll
  for (int u = 0; u < 4; ++u) {
    float s0, c0, s1, c1;
    __sincosf((float)((k * (l0 + 2 * u)) & 8191) * W0, &s0, &c0);
    __sincosf((float)((k * (l0 + 2 * u + 1)) & 8191) * W0, &s1, &c1);
    const unsigned short b0 = f2bf((j & 1) ? (-a * s0) : (a * c0));
    const unsigned short b1 = f2bf((j & 1) ? (-a * s1) : (a * c1));
    w[u] = (uint32_t)b0 | ((uint32_t)b1 << 16);
  }
  uint4 v; v.x = w[0]; v.y = w[1]; v.z = w[2]; v.w = w[3];
  *(uint4*)(Bf + e0) = v;
}

// ---------------------------------------------------------------------------
// k1 v3: per (b, chunk p, channel-half h): XFP[p][b][c 64][j 128] +=
// Bf[128][512] @ x[b][512][32ch]. Channel split halves LDS (33 KiB -> 4
// blocks/CU = 16 waves/CU vs 2 before) and makes stage reads full 128 B
// segments. Output stored TRANSPOSED [c][j] as f32x4 (reg axis j contiguous).
// ---------------------------------------------------------------------------
__global__ __launch_bounds__(256) void k1_dft(const float* __restrict__ x,
                                              const unsigned short* __restrict__ Bf,
                                              float* __restrict__ XFP) {
  const int b = blockIdx.x >> 5;
  const int p = (blockIdx.x >> 1) & 15;
  const int h = blockIdx.x & 1;            // channel half: c in [h*32, h*32+32)
  const int l0 = p * CHUNK;
  const int t = threadIdx.x;
  const int wv = t >> 6, lane = t & 63, q = lane >> 4, n = lane & 15;
  __shared__ uint32_t sx[32 * (SXPAD / 2)];   // [c_local][l] bf16, l-pairs packed
  const float* xb = x + (size_t)b * L_ * NC + h * 32;

  {                                          // stage + transpose (32 channels)
    const int g  = t & 7;                    // channel group (4 ch)
    const int r2 = t >> 3;                   // row-pair 0..31
    #pragma unroll
    for (int s = 0; s < 8; ++s) {            // 8 batches of 64 l-rows
      const int lp = s * 32 + r2;            // pair index 0..255
      const f32x4 u0 = *(const f32x4*)(xb + (size_t)(l0 + 2 * lp) * NC + 4 * g);
      const f32x4 u1 = *(const f32x4*)(xb + (size_t)(l0 + 2 * lp + 1) * NC + 4 * g);
      #pragma unroll
      for (int jj = 0; jj < 4; ++jj) {
        __bf16 pk2[2] = {(__bf16)u0[jj], (__bf16)u1[jj]};
        sx[(4 * g + jj) * (SXPAD / 2) + lp] = __builtin_bit_cast(uint32_t, pk2);
      }
    }
  }
  __syncthreads();

  f32x4 acc[2][2];
  #pragma unroll
  for (int i = 0; i < 2; ++i)
    #pragma unroll
    for (int jn = 0; jn < 2; ++jn) acc[i][jn] = (f32x4){0.f, 0.f, 0.f, 0.f};
  const unsigned short* sxu = (const unsigned short*)sx;

  for (int ks = 0; ks < CHUNK; ks += 32) {
    const int lb = ks + q * 8;
    const bf16x8 bfr0 = *(const bf16x8*)(sxu + (n)      * SXPAD + lb);
    const bf16x8 bfr1 = *(const bf16x8*)(sxu + (16 + n) * SXPAD + lb);
    #pragma unroll
    for (int mt = 0; mt < 2; ++mt) {         // A-frag: wave-private Bf rows
      const bf16x8 afr = *(const bf16x8*)(Bf + (size_t)(wv * 32 + mt * 16 + n) * L_ + l0 + lb);
      acc[mt][0] = mfma16(afr, bfr0, acc[mt][0]);
      acc[mt][1] = mfma16(afr, bfr1, acc[mt][1]);
    }
  }

  // D layout: row(M)=mode j = wv*32+mt*16+q*4+r, col(N)=c_local = nt*16+n.
  // Store transposed [c][j]: r walks contiguous j -> f32x4 stores.
  float* op = XFP + (size_t)(p * NB + b) * 8192;
  #pragma unroll
  for (int mt = 0; mt < 2; ++mt)
    #pragma unroll
    for (int nt = 0; nt < 2; ++nt)
      *(f32x4*)(op + (size_t)(h * 32 + nt * 16 + n) * 128 + (wv * 32 + mt * 16 + q * 4)) =
          acc[mt][nt];
}

// ---------------------------------------------------------------------------
// k1b: XFR = sum_p XFP[p]. f32x4 lanes, 16 independent streams, coalesced.
// Layout-agnostic elementwise reduce -> XFR inherits [b][c][j].
// ---------------------------------------------------------------------------
__global__ __launch_bounds__(256) void k1b_red(const f32x4* __restrict__ XFP,
                                               f32x4* __restrict__ XFR) {
  const int idx = blockIdx.x * 256 + threadIdx.x;    // 65536 f32x4 total
  f32x4 s = XFP[idx];
  #pragma unroll
  for (int p = 1; p < SPLITK; ++p) {
    const f32x4 v = XFP[(size_t)p * 65536 + idx];
    s[0] += v[0]; s[1] += v[1]; s[2] += v[2]; s[3] += v[3];
  }
  XFR[idx] = s;
}

// ---------------------------------------------------------------------------
// k2 v2: LDS-free mode mix. XFR is [b][c][2m] so (re,im) is one coalesced
// float2 load. Block (b, og4): 4 waves = 4 output channels, lane = mode.
// TF[o][m] = sum_i XF[i][m] * W[i][o][m]; pack re/im bf16 + pw rows.
// ---------------------------------------------------------------------------
__global__ __launch_bounds__(256) void k2_mix(const float* __restrict__ XFR,
                                              const float* __restrict__ wr,
                                              const float* __restrict__ wi,
                                              const float* __restrict__ pww,
                                              uint32_t* __restrict__ tf_stage) {
  const int b = blockIdx.x >> 4;
  const int og = blockIdx.x & 15;
  const int t = threadIdx.x;
  const int k = t & 63;                      // mode (lane)
  const int wv = t >> 6;
  const int o = og * 4 + wv;                 // output channel
  const float2* xfb = (const float2*)(XFR + (size_t)b * 8192);   // [c][64 pairs]
  float ar = 0.f, ai = 0.f;
  #pragma unroll 8
  for (int i = 0; i < 64; ++i) {             // input channel
    const float2 xv  = xfb[i * 64 + k];      // (re, im) -- 8B coalesced
    const float  wrv = wr[(size_t)i * 4096 + o * 64 + k];
    const float  wiv = wi[(size_t)i * 4096 + o * 64 + k];
    ar = fmaf(xv.x, wrv, ar);  ar = fmaf(-xv.y, wiv, ar);
    ai = fmaf(xv.x, wiv, ai);  ai = fmaf(xv.y, wrv, ai);
  }
  uint32_t* row = tf_stage + ((size_t)b * 64 + o) * 96;
  row[k] = (uint32_t)f2bf(ar) | ((uint32_t)f2bf(ai) << 16);
  if (k < 32)                                // pw rows: bf16 pairs [64..96)
    row[64 + k] = (uint32_t)f2bf(pww[o * 64 + 2 * k]) |
                  ((uint32_t)f2bf(pww[o * 64 + 2 * k + 1]) << 16);
}

// ---------------------------------------------------------------------------
// k2b: bridge TF staging (768 KiB in d_out) into the dead wr input buffer
// (1 MiB) so k3 never reads d_out.
// ---------------------------------------------------------------------------
__global__ __launch_bounds__(256) void k2b_copy(const uint4* __restrict__ src,
                                                uint4* __restrict__ dst) {
  const int idx = blockIdx.x * 256 + threadIdx.x;   // 49152 uint4 = 768 KiB
  dst[idx] = src[idx];
}

// ---------------------------------------------------------------------------
// k3 v2: swapped-operand MFMA. D[c][l] = TF[b] (64x192) @ [Bi | x]^T, so the
// C-fragment register axis lands on the contiguous c axis -> f32x4 stores
// (8 per thread vs 32 scalar). Load/sincos cost identical to v1.
// ---------------------------------------------------------------------------
__global__ __launch_bounds__(256) void k3_out(const float* __restrict__ x,
                                              const unsigned short* __restrict__ tf,
                                              const float* __restrict__ bias,
                                              float* __restrict__ out) {
  const int b = blockIdx.x >> 6;
  const int lt = blockIdx.x & 63;
  const int wv = threadIdx.x >> 6;
  const int lane = threadIdx.x & 63;
  const int q = lane >> 4;
  const int n = lane & 15;
  const int l0 = lt * 128 + wv * 32;   // wave: 32 l-cols x 64 c-rows
  const float* xb = x + (size_t)b * L_ * NC;
  const unsigned short* tfb = tf + (size_t)b * 64 * 192;
  const float W0 = 6.283185307179586f / 8192.0f;
  f32x4 acc[4][2];                     // [c-tile mt][l-tile nt]
  #pragma unroll
  for (int i = 0; i < 4; ++i)
    #pragma unroll
    for (int jn = 0; jn < 2; ++jn) acc[i][jn] = (f32x4){0.f, 0.f, 0.f, 0.f};
  const int lA = l0 + n;               // l for nt=0 (B-frag col = lane n)
  const int lB = l0 + 16 + n;          // l for nt=1
  #pragma unroll
  for (int s = 0; s < 6; ++s) {
    const int k0 = s * 32;
    bf16x8 b0, b1;
    if (s < 4) {                       // spectral: Bi[k][l] on the fly
      #pragma unroll
      for (int jj = 0; jj < 4; ++jj) {
        const int kf = (k0 >> 1) + q * 4 + jj;
        float sv, cv;
        __sincosf((float)((kf * lA) & 8191) * W0, &sv, &cv);
        b0[2 * jj] = (__bf16)cv; b0[2 * jj + 1] = (__bf16)(-sv);
        __sincosf((float)((kf * lB) & 8191) * W0, &sv, &cv);
        b1[2 * jj] = (__bf16)cv; b1[2 * jj + 1] = (__bf16)(-sv);
      }
    } else {                           // pointwise: x rows, float4 + native cvt
      const int cc = (k0 - 128) + q * 8;
      const f32x4* p0 = (const f32x4*)(xb + (size_t)lA * NC + cc);
      const f32x4* p1 = (const f32x4*)(xb + (size_t)lB * NC + cc);
      const f32x4 u00 = p0[0], u01 = p0[1], u10 = p1[0], u11 = p1[1];
      #pragma unroll
      for (int jj = 0; jj < 4; ++jj) {
        b0[jj] = (__bf16)u00[jj]; b0[4 + jj] = (__bf16)u01[jj];
        b1[jj] = (__bf16)u10[jj]; b1[4 + jj] = (__bf16)u11[jj];
      }
    }
    #pragma unroll
    for (int mt = 0; mt < 4; ++mt) {   // A-frag: TF row mt*16+n, k at k0+q*8
      const bf16x8 afr = *(const bf16x8*)(tfb + (size_t)(mt * 16 + n) * 192 + k0 + q * 8);
      acc[mt][0] = mfma16(afr, b0, acc[mt][0]);
      acc[mt][1] = mfma16(afr, b1, acc[mt][1]);
    }
  }
  float* ob = out + (size_t)b * L_ * NC;
  #pragma unroll
  for (int mt = 0; mt < 4; ++mt) {
    const f32x4 bv = *(const f32x4*)(bias + mt * 16 + q * 4);
    #pragma unroll
    for (int nt = 0; nt < 2; ++nt) {
      const int l = l0 + nt * 16 + n;
      f32x4 v = acc[mt][nt];
      v[0] += bv[0]; v[1] += bv[1]; v[2] += bv[2]; v[3] += bv[3];
      *(f32x4*)(ob + (size_t)l * NC + mt * 16 + q * 4) = v;
    }
  }
}

// ---------------------------------------------------------------------------
extern "C" void kernel_launch(void* const* d_in, const int* in_sizes, int n_in,
                              void* d_out, int out_size, void* d_ws, size_t ws_size,
                              hipStream_t stream) {
  (void)in_sizes; (void)n_in; (void)out_size; (void)d_ws; (void)ws_size;
  const float* x    = (const float*)d_in[0];
  float*       wr   = (float*)d_in[1];        // dead after k2 -> TF bridge
  const float* wi   = (const float*)d_in[2];
  const float* pww  = (const float*)d_in[3];
  const float* bias = (const float*)d_in[4];
  float* out = (float*)d_out;

  char* ob = (char*)d_out;
  unsigned short* Bf  = (unsigned short*)(ob + BF_OFF);
  float*          XFP = (float*)(ob + XF_OFF);
  float*          XFR = (float*)(ob + XR_OFF);
  uint32_t*       TFS = (uint32_t*)(ob + TF_OFF);

  k0_bf   <<<512,             256, 0, stream>>>(Bf);
  k1_dft  <<<NB * SPLITK * 2, 256, 0, stream>>>(x, Bf, XFP);
  k1b_red <<<256,             256, 0, stream>>>((const f32x4*)XFP, (f32x4*)XFR);
  k2_mix  <<<NB * 16,         256, 0, stream>>>(XFR, wr, wi, pww, TFS);
  k2b_copy<<<192,             256, 0, stream>>>((const uint4*)TFS, (uint4*)wr);
  k3_out  <<<NB * 64,         256, 0, stream>>>(x, (const unsigned short*)wr, bias, out);
}

// Round 3
// 184.923 us; speedup vs baseline: 1.0863x; 1.0863x over previous
//
#include <hip/hip_runtime.h>
#include <stdint.h>

// Problem constants: B=32, L=8192, C=64, M=64. All I/O fp32.
#define L_     8192
#define NB     32
#define NC     64
#define SPLITK 16
#define CHUNK  (L_ / SPLITK)   // 512
#define SXPAD  520             // LDS row stride (bf16 elems): 512 + 8 pad

// d_out (64 MiB fp32) doubles as scratch for k0..k2; k3 overwrites all of it
// and reads none of it (TF bridged through the dead wr input buffer by k2b).
#define BF_OFF  0            // Bf table:    128 x 8192 bf16 = 2 MiB
#define XF_OFF  (2u  << 20)  // XF partials: 16 x 32 x 8192 fp32 = 16 MiB
#define XR_OFF  (18u << 20)  // XF reduced:  32 x 8192 fp32 = 1 MiB   [c][j] layout
#define TF_OFF  (19u << 20)  // TF staging:  32 x 64 x 192 bf16 = 768 KiB

typedef __bf16 bf16x8 __attribute__((ext_vector_type(8)));
typedef float  f32x4  __attribute__((ext_vector_type(4)));

__device__ __forceinline__ unsigned short f2bf(float f) {
  union { float f; unsigned int i; } v; v.f = f;
  unsigned int r = v.i + 0x7fffu + ((v.i >> 16) & 1u);  // RNE (cold paths)
  return (unsigned short)(r >> 16);
}
__device__ __forceinline__ f32x4 mfma16(bf16x8 a, bf16x8 b, f32x4 c) {
  return __builtin_amdgcn_mfma_f32_16x16x32_bf16(a, b, c, 0, 0, 0);
}

// ---------------------------------------------------------------------------
// k0: forward DFT basis Bf[j][l] (bf16): j=2k: a_k cos(2pi k l/L), j=2k+1:
// -a_k sin. a_k = (k==0?1:2)/L folds the irfft normalization forward.
// ---------------------------------------------------------------------------
__global__ __launch_bounds__(256) void k0_bf(unsigned short* __restrict__ Bf) {
  const int e0 = (blockIdx.x * 256 + threadIdx.x) * 8;
  const int j = e0 >> 13, l0 = e0 & 8191, k = j >> 1;
  const float W0 = 6.283185307179586f / 8192.0f;
  const float a = (k == 0 ? 1.0f : 2.0f) * (1.0f / 8192.0f);
  uint32_t w[4];
  #pragma unroll
  for (int u = 0; u < 4; ++u) {
    float s0, c0, s1, c1;
    __sincosf((float)((k * (l0 + 2 * u)) & 8191) * W0, &s0, &c0);
    __sincosf((float)((k * (l0 + 2 * u + 1)) & 8191) * W0, &s1, &c1);
    const unsigned short b0 = f2bf((j & 1) ? (-a * s0) : (a * c0));
    const unsigned short b1 = f2bf((j & 1) ? (-a * s1) : (a * c1));
    w[u] = (uint32_t)b0 | ((uint32_t)b1 << 16);
  }
  uint4 v; v.x = w[0]; v.y = w[1]; v.z = w[2]; v.w = w[3];
  *(uint4*)(Bf + e0) = v;
}

// ---------------------------------------------------------------------------
// k1 v4: round-0 measured shape (full 64 channels, 512 blocks, 66.5 KiB LDS,
// 8 MFMA per A-frag pair) + transposed [c][j] f32x4 stores (k2 v2's layout).
// ---------------------------------------------------------------------------
__global__ __launch_bounds__(256) void k1_dft(const float* __restrict__ x,
                                              const unsigned short* __restrict__ Bf,
                                              float* __restrict__ XFP) {
  const int b = blockIdx.x >> 4;
  const int p = blockIdx.x & 15;
  const int l0 = p * CHUNK;
  const int t = threadIdx.x;
  const int wv = t >> 6, lane = t & 63, q = lane >> 4, n = lane & 15;
  __shared__ uint32_t sx[NC * SXPAD / 2];   // [c][l] bf16, l-pairs packed
  const float* xb = x + (size_t)b * L_ * NC;

  {                                          // stage + transpose
    const int g  = t & 15;                   // channel group (4 ch)
    const int r2 = t >> 4;                   // row-pair 0..15
    for (int s = 0; s < 16; ++s) {           // 16 batches of 32 l-rows
      const int lrow = s * 32 + 2 * r2;
      const f32x4 u0 = *(const f32x4*)(xb + (size_t)(l0 + lrow) * NC + 4 * g);
      const f32x4 u1 = *(const f32x4*)(xb + (size_t)(l0 + lrow + 1) * NC + 4 * g);
      #pragma unroll
      for (int jj = 0; jj < 4; ++jj) {
        __bf16 pk2[2] = {(__bf16)u0[jj], (__bf16)u1[jj]};
        sx[(4 * g + jj) * (SXPAD / 2) + s * 16 + r2] = __builtin_bit_cast(uint32_t, pk2);
      }
    }
  }
  __syncthreads();

  f32x4 acc[2][4];
  #pragma unroll
  for (int i = 0; i < 2; ++i)
    #pragma unroll
    for (int jn = 0; jn < 4; ++jn) acc[i][jn] = (f32x4){0.f, 0.f, 0.f, 0.f};
  const unsigned short* sxu = (const unsigned short*)sx;

  for (int ks = 0; ks < CHUNK; ks += 32) {
    const int lb = ks + q * 8;
    bf16x8 bfr[4];
    #pragma unroll
    for (int nt = 0; nt < 4; ++nt)           // B-frag: 16B LDS reads
      bfr[nt] = *(const bf16x8*)(sxu + (nt * 16 + n) * SXPAD + lb);
    #pragma unroll
    for (int mt = 0; mt < 2; ++mt) {         // A-frag: wave-private Bf rows
      const bf16x8 afr = *(const bf16x8*)(Bf + (size_t)(wv * 32 + mt * 16 + n) * L_ + l0 + lb);
      #pragma unroll
      for (int nt = 0; nt < 4; ++nt)
        acc[mt][nt] = mfma16(afr, bfr[nt], acc[mt][nt]);
    }
  }

  // D layout: row(M)=mode j = wv*32+mt*16+q*4+r, col(N)=c = nt*16+n.
  // Store transposed [c][j]: r walks contiguous j -> f32x4 stores.
  float* op = XFP + (size_t)(p * NB + b) * 8192;
  #pragma unroll
  for (int mt = 0; mt < 2; ++mt)
    #pragma unroll
    for (int nt = 0; nt < 4; ++nt)
      *(f32x4*)(op + (size_t)(nt * 16 + n) * 128 + (wv * 32 + mt * 16 + q * 4)) =
          acc[mt][nt];
}

// ---------------------------------------------------------------------------
// k1b: XFR = sum_p XFP[p]. f32x4 lanes, coalesced. Layout-agnostic reduce ->
// XFR inherits [b][c][j].
// ---------------------------------------------------------------------------
__global__ __launch_bounds__(256) void k1b_red(const f32x4* __restrict__ XFP,
                                               f32x4* __restrict__ XFR) {
  const int idx = blockIdx.x * 256 + threadIdx.x;    // 65536 f32x4 total
  f32x4 s = XFP[idx];
  #pragma unroll
  for (int p = 1; p < SPLITK; ++p) {
    const f32x4 v = XFP[(size_t)p * 65536 + idx];
    s[0] += v[0]; s[1] += v[1]; s[2] += v[2]; s[3] += v[3];
  }
  XFR[idx] = s;
}

// ---------------------------------------------------------------------------
// k2 v2: LDS-free mode mix. XFR is [b][c][2m] so (re,im) is one coalesced
// float2 load. Block (b, og4): 4 waves = 4 output channels, lane = mode.
// ---------------------------------------------------------------------------
__global__ __launch_bounds__(256) void k2_mix(const float* __restrict__ XFR,
                                              const float* __restrict__ wr,
                                              const float* __restrict__ wi,
                                              const float* __restrict__ pww,
                                              uint32_t* __restrict__ tf_stage) {
  const int b = blockIdx.x >> 4;
  const int og = blockIdx.x & 15;
  const int t = threadIdx.x;
  const int k = t & 63;                      // mode (lane)
  const int wv = t >> 6;
  const int o = og * 4 + wv;                 // output channel
  const float2* xfb = (const float2*)(XFR + (size_t)b * 8192);   // [c][64 pairs]
  float ar = 0.f, ai = 0.f;
  #pragma unroll 8
  for (int i = 0; i < 64; ++i) {             // input channel
    const float2 xv  = xfb[i * 64 + k];      // (re, im) -- 8B coalesced
    const float  wrv = wr[(size_t)i * 4096 + o * 64 + k];
    const float  wiv = wi[(size_t)i * 4096 + o * 64 + k];
    ar = fmaf(xv.x, wrv, ar);  ar = fmaf(-xv.y, wiv, ar);
    ai = fmaf(xv.x, wiv, ai);  ai = fmaf(xv.y, wrv, ai);
  }
  uint32_t* row = tf_stage + ((size_t)b * 64 + o) * 96;
  row[k] = (uint32_t)f2bf(ar) | ((uint32_t)f2bf(ai) << 16);
  if (k < 32)                                // pw rows: bf16 pairs [64..96)
    row[64 + k] = (uint32_t)f2bf(pww[o * 64 + 2 * k]) |
                  ((uint32_t)f2bf(pww[o * 64 + 2 * k + 1]) << 16);
}

// ---------------------------------------------------------------------------
// k2b: bridge TF staging (768 KiB in d_out) into the dead wr input buffer
// (1 MiB) so k3 never reads d_out.
// ---------------------------------------------------------------------------
__global__ __launch_bounds__(256) void k2b_copy(const uint4* __restrict__ src,
                                                uint4* __restrict__ dst) {
  const int idx = blockIdx.x * 256 + threadIdx.x;   // 49152 uint4 = 768 KiB
  dst[idx] = src[idx];
}

// ---------------------------------------------------------------------------
// k3 v3: latency fix for the measured 41.7us / 31% HBM / 38.7% occ profile.
// (a) TF staged into LDS once per block (rows padded 192->200 bf16: b128 read
//     window (n+q+c)%8 balanced -> conflict-free-equivalent); A-frags become
//     ~12cy ds_reads instead of per-iteration L2 round-trips.
// (b) All 8 pointwise x f32x4 loads issued at kernel entry; their HBM latency
//     hides under the TF stage + s=0..3 sincos compute.
// ---------------------------------------------------------------------------
__global__ __launch_bounds__(256) void k3_out(const float* __restrict__ x,
                                              const unsigned short* __restrict__ tf,
                                              const float* __restrict__ bias,
                                              float* __restrict__ out) {
  const int b = blockIdx.x >> 6;
  const int lt = blockIdx.x & 63;
  const int t = threadIdx.x;
  const int wv = t >> 6;
  const int lane = t & 63;
  const int q = lane >> 4;
  const int n = lane & 15;
  const int l0 = lt * 128 + wv * 32;   // wave: 32 l-cols x 64 c-rows
  const float* xb = x + (size_t)b * L_ * NC;
  const unsigned short* tfb = tf + (size_t)b * 64 * 192;
  const float W0 = 6.283185307179586f / 8192.0f;
  const int lA = l0 + n;               // l for nt=0 (B-frag col = lane n)
  const int lB = l0 + 16 + n;          // l for nt=1

  // (b) hoist pointwise x loads (consumed at s=4,5)
  const f32x4* pA0 = (const f32x4*)(xb + (size_t)lA * NC + q * 8);
  const f32x4* pB0 = (const f32x4*)(xb + (size_t)lB * NC + q * 8);
  const f32x4* pA1 = (const f32x4*)(xb + (size_t)lA * NC + 32 + q * 8);
  const f32x4* pB1 = (const f32x4*)(xb + (size_t)lB * NC + 32 + q * 8);
  const f32x4 xA00 = pA0[0], xA01 = pA0[1];
  const f32x4 xB00 = pB0[0], xB01 = pB0[1];
  const f32x4 xA10 = pA1[0], xA11 = pA1[1];
  const f32x4 xB10 = pB1[0], xB11 = pB1[1];

  // (a) stage TF into LDS, rows padded 192 -> 200 bf16 (25.6 KiB)
  __shared__ unsigned short stf[64 * 200];
  {
    uint4* dst = (uint4*)stf;
    const uint4* src = (const uint4*)tfb;    // 1536 uint4 = 24 KiB
    #pragma unroll
    for (int i = 0; i < 6; ++i) {
      const int e4 = t + i * 256;
      const int row = e4 / 24, c4 = e4 - row * 24;   // 24 uint4 per 192-bf16 row
      dst[row * 25 + c4] = src[e4];                  // dst row stride 25 uint4
    }
  }
  __syncthreads();

  f32x4 acc[4][2];                     // [c-tile mt][l-tile nt]
  #pragma unroll
  for (int i = 0; i < 4; ++i)
    #pragma unroll
    for (int jn = 0; jn < 2; ++jn) acc[i][jn] = (f32x4){0.f, 0.f, 0.f, 0.f};

  #pragma unroll
  for (int s = 0; s < 6; ++s) {
    const int k0 = s * 32;
    bf16x8 b0, b1;
    if (s < 4) {                       // spectral: Bi[k][l] on the fly
      #pragma unroll
      for (int jj = 0; jj < 4; ++jj) {
        const int kf = (k0 >> 1) + q * 4 + jj;
        float sv, cv;
        __sincosf((float)((kf * lA) & 8191) * W0, &sv, &cv);
        b0[2 * jj] = (__bf16)cv; b0[2 * jj + 1] = (__bf16)(-sv);
        __sincosf((float)((kf * lB) & 8191) * W0, &sv, &cv);
        b1[2 * jj] = (__bf16)cv; b1[2 * jj + 1] = (__bf16)(-sv);
      }
    } else if (s == 4) {               // pointwise: hoisted x regs
      #pragma unroll
      for (int jj = 0; jj < 4; ++jj) {
        b0[jj] = (__bf16)xA00[jj]; b0[4 + jj] = (__bf16)xA01[jj];
        b1[jj] = (__bf16)xB00[jj]; b1[4 + jj] = (__bf16)xB01[jj];
      }
    } else {
      #pragma unroll
      for (int jj = 0; jj < 4; ++jj) {
        b0[jj] = (__bf16)xA10[jj]; b0[4 + jj] = (__bf16)xA11[jj];
        b1[jj] = (__bf16)xB10[jj]; b1[4 + jj] = (__bf16)xB11[jj];
      }
    }
    #pragma unroll
    for (int mt = 0; mt < 4; ++mt) {   // A-frag: TF row mt*16+n from LDS
      const bf16x8 afr = *(const bf16x8*)(stf + (mt * 16 + n) * 200 + k0 + q * 8);
      acc[mt][0] = mfma16(afr, b0, acc[mt][0]);
      acc[mt][1] = mfma16(afr, b1, acc[mt][1]);
    }
  }
  float* ob = out + (size_t)b * L_ * NC;
  #pragma unroll
  for (int mt = 0; mt < 4; ++mt) {
    const f32x4 bv = *(const f32x4*)(bias + mt * 16 + q * 4);
    #pragma unroll
    for (int nt = 0; nt < 2; ++nt) {
      const int l = l0 + nt * 16 + n;
      f32x4 v = acc[mt][nt];
      v[0] += bv[0]; v[1] += bv[1]; v[2] += bv[2]; v[3] += bv[3];
      *(f32x4*)(ob + (size_t)l * NC + mt * 16 + q * 4) = v;
    }
  }
}

// ---------------------------------------------------------------------------
extern "C" void kernel_launch(void* const* d_in, const int* in_sizes, int n_in,
                              void* d_out, int out_size, void* d_ws, size_t ws_size,
                              hipStream_t stream) {
  (void)in_sizes; (void)n_in; (void)out_size; (void)d_ws; (void)ws_size;
  const float* x    = (const float*)d_in[0];
  float*       wr   = (float*)d_in[1];        // dead after k2 -> TF bridge
  const float* wi   = (const float*)d_in[2];
  const float* pww  = (const float*)d_in[3];
  const float* bias = (const float*)d_in[4];
  float* out = (float*)d_out;

  char* ob = (char*)d_out;
  unsigned short* Bf  = (unsigned short*)(ob + BF_OFF);
  float*          XFP = (float*)(ob + XF_OFF);
  float*          XFR = (float*)(ob + XR_OFF);
  uint32_t*       TFS = (uint32_t*)(ob + TF_OFF);

  k0_bf   <<<512,         256, 0, stream>>>(Bf);
  k1_dft  <<<NB * SPLITK, 256, 0, stream>>>(x, Bf, XFP);
  k1b_red <<<256,         256, 0, stream>>>((const f32x4*)XFP, (f32x4*)XFR);
  k2_mix  <<<NB * 16,     256, 0, stream>>>(XFR, wr, wi, pww, TFS);
  k2b_copy<<<192,         256, 0, stream>>>((const uint4*)TFS, (uint4*)wr);
  k3_out  <<<NB * 64,     256, 0, stream>>>(x, (const unsigned short*)wr, bias, out);
}

// Round 4
// 162.931 us; speedup vs baseline: 1.2330x; 1.1350x over previous
//
#include <hip/hip_runtime.h>
#include <stdint.h>

// Problem constants: B=32, L=8192, C=64, M=64. All I/O fp32.
#define L_     8192
#define NB     32
#define NC     64
#define SPLITK 16
#define CHUNK  (L_ / SPLITK)   // 512
#define SXPAD  520             // LDS row stride (bf16 elems): 512 + 8 pad

// d_out (64 MiB fp32) doubles as scratch for k0..k2; k3 overwrites all of it
// and reads none of it (TF written directly into the dead wr input buffer;
// k2 reads weights from the WC copy made by k0).
#define BF_OFF  0            // Bf table:    128 x 8192 bf16 = 2 MiB
#define XF_OFF  (2u  << 20)  // XF partials: 16 x 32 x 8192 fp32 = 16 MiB
#define XR_OFF  (18u << 20)  // XF reduced:  32 x 8192 fp32 = 1 MiB   [c][j] layout
#define WC_OFF  (19u << 20)  // wr copy:     1 MiB (read by k2 instead of wr)

typedef __bf16 bf16x8 __attribute__((ext_vector_type(8)));
typedef float  f32x4  __attribute__((ext_vector_type(4)));

__device__ __forceinline__ unsigned short f2bf(float f) {
  union { float f; unsigned int i; } v; v.f = f;
  unsigned int r = v.i + 0x7fffu + ((v.i >> 16) & 1u);  // RNE (cold paths)
  return (unsigned short)(r >> 16);
}
__device__ __forceinline__ f32x4 mfma16(bf16x8 a, bf16x8 b, f32x4 c) {
  return __builtin_amdgcn_mfma_f32_16x16x32_bf16(a, b, c, 0, 0, 0);
}

// ---------------------------------------------------------------------------
// k0: forward DFT basis Bf[j][l] (bf16): j=2k: a_k cos(2pi k l/L), j=2k+1:
// -a_k sin. a_k = (k==0?1:2)/L folds the irfft normalization forward.
// Also copies wr (1 MiB) -> WC scratch so k2 can overwrite wr with TF.
// ---------------------------------------------------------------------------
__global__ __launch_bounds__(256) void k0_bf(unsigned short* __restrict__ Bf,
                                             const uint2* __restrict__ wrsrc,
                                             uint2* __restrict__ wc) {
  const int t = blockIdx.x * 256 + threadIdx.x;
  const int e0 = t * 8;
  const int j = e0 >> 13, l0 = e0 & 8191, k = j >> 1;
  const float W0 = 6.283185307179586f / 8192.0f;
  const float a = (k == 0 ? 1.0f : 2.0f) * (1.0f / 8192.0f);
  uint32_t w[4];
  #pragma unroll
  for (int u = 0; u < 4; ++u) {
    float s0, c0, s1, c1;
    __sincosf((float)((k * (l0 + 2 * u)) & 8191) * W0, &s0, &c0);
    __sincosf((float)((k * (l0 + 2 * u + 1)) & 8191) * W0, &s1, &c1);
    const unsigned short b0 = f2bf((j & 1) ? (-a * s0) : (a * c0));
    const unsigned short b1 = f2bf((j & 1) ? (-a * s1) : (a * c1));
    w[u] = (uint32_t)b0 | ((uint32_t)b1 << 16);
  }
  uint4 v; v.x = w[0]; v.y = w[1]; v.z = w[2]; v.w = w[3];
  *(uint4*)(Bf + e0) = v;
  wc[t] = wrsrc[t];                    // 131072 uint2 = 1 MiB copy
}

// ---------------------------------------------------------------------------
// k1 v4: round-0 measured shape (full 64 channels, 512 blocks, 66.5 KiB LDS,
// 8 MFMA per A-frag pair) + transposed [c][j] f32x4 stores (k2's layout).
// ---------------------------------------------------------------------------
__global__ __launch_bounds__(256) void k1_dft(const float* __restrict__ x,
                                              const unsigned short* __restrict__ Bf,
                                              float* __restrict__ XFP) {
  const int b = blockIdx.x >> 4;
  const int p = blockIdx.x & 15;
  const int l0 = p * CHUNK;
  const int t = threadIdx.x;
  const int wv = t >> 6, lane = t & 63, q = lane >> 4, n = lane & 15;
  __shared__ uint32_t sx[NC * SXPAD / 2];   // [c][l] bf16, l-pairs packed
  const float* xb = x + (size_t)b * L_ * NC;

  {                                          // stage + transpose
    const int g  = t & 15;                   // channel group (4 ch)
    const int r2 = t >> 4;                   // row-pair 0..15
    for (int s = 0; s < 16; ++s) {           // 16 batches of 32 l-rows
      const int lrow = s * 32 + 2 * r2;
      const f32x4 u0 = *(const f32x4*)(xb + (size_t)(l0 + lrow) * NC + 4 * g);
      const f32x4 u1 = *(const f32x4*)(xb + (size_t)(l0 + lrow + 1) * NC + 4 * g);
      #pragma unroll
      for (int jj = 0; jj < 4; ++jj) {
        __bf16 pk2[2] = {(__bf16)u0[jj], (__bf16)u1[jj]};
        sx[(4 * g + jj) * (SXPAD / 2) + s * 16 + r2] = __builtin_bit_cast(uint32_t, pk2);
      }
    }
  }
  __syncthreads();

  f32x4 acc[2][4];
  #pragma unroll
  for (int i = 0; i < 2; ++i)
    #pragma unroll
    for (int jn = 0; jn < 4; ++jn) acc[i][jn] = (f32x4){0.f, 0.f, 0.f, 0.f};
  const unsigned short* sxu = (const unsigned short*)sx;

  for (int ks = 0; ks < CHUNK; ks += 32) {
    const int lb = ks + q * 8;
    bf16x8 bfr[4];
    #pragma unroll
    for (int nt = 0; nt < 4; ++nt)           // B-frag: 16B LDS reads
      bfr[nt] = *(const bf16x8*)(sxu + (nt * 16 + n) * SXPAD + lb);
    #pragma unroll
    for (int mt = 0; mt < 2; ++mt) {         // A-frag: wave-private Bf rows
      const bf16x8 afr = *(const bf16x8*)(Bf + (size_t)(wv * 32 + mt * 16 + n) * L_ + l0 + lb);
      #pragma unroll
      for (int nt = 0; nt < 4; ++nt)
        acc[mt][nt] = mfma16(afr, bfr[nt], acc[mt][nt]);
    }
  }

  // D layout: row(M)=mode j = wv*32+mt*16+q*4+r, col(N)=c = nt*16+n.
  // Store transposed [c][j]: r walks contiguous j -> f32x4 stores.
  float* op = XFP + (size_t)(p * NB + b) * 8192;
  #pragma unroll
  for (int mt = 0; mt < 2; ++mt)
    #pragma unroll
    for (int nt = 0; nt < 4; ++nt)
      *(f32x4*)(op + (size_t)(nt * 16 + n) * 128 + (wv * 32 + mt * 16 + q * 4)) =
          acc[mt][nt];
}

// ---------------------------------------------------------------------------
// k1b: XFR = sum_p XFP[p]. f32x4 lanes, coalesced. Layout-agnostic reduce ->
// XFR inherits [b][c][j].
// ---------------------------------------------------------------------------
__global__ __launch_bounds__(256) void k1b_red(const f32x4* __restrict__ XFP,
                                               f32x4* __restrict__ XFR) {
  const int idx = blockIdx.x * 256 + threadIdx.x;    // 65536 f32x4 total
  f32x4 s = XFP[idx];
  #pragma unroll
  for (int p = 1; p < SPLITK; ++p) {
    const f32x4 v = XFP[(size_t)p * 65536 + idx];
    s[0] += v[0]; s[1] += v[1]; s[2] += v[2]; s[3] += v[3];
  }
  XFR[idx] = s;
}

// ---------------------------------------------------------------------------
// k2 v3: v1's LDS-staged structure, layout-matched to [c][2m] XFR: the 32 KiB
// stage is a straight contiguous copy (no transpose), inner loop reads LDS
// float2 (8 B/lane = 2-way bank alias, free) + only TWO global streams
// (weights). 256 blocks, 8 o/block, 32 KiB LDS -> 5 blocks/CU.
// Weights read from WC copy; TF written directly into the dead wr buffer.
// ---------------------------------------------------------------------------
__global__ __launch_bounds__(256) void k2_mix(const float* __restrict__ XFR,
                                              const float* __restrict__ wc,
                                              const float* __restrict__ wi,
                                              const float* __restrict__ pww,
                                              uint32_t* __restrict__ tf_out) {
  const int b = blockIdx.x >> 3;
  const int og = blockIdx.x & 7;
  const int t = threadIdx.x;
  const int k = t & 63;                      // mode (lane)
  const int wv = t >> 6;
  __shared__ float sxf[8192];                // XFR[b] as-is: [c][2m], 32 KiB
  {
    f32x4* d = (f32x4*)sxf;
    const f32x4* s = (const f32x4*)(XFR + (size_t)b * 8192);
    #pragma unroll
    for (int i = 0; i < 8; ++i) d[t + i * 256] = s[t + i * 256];
  }
  __syncthreads();
  #pragma unroll
  for (int oo = 0; oo < 2; ++oo) {
    const int o = og * 8 + wv * 2 + oo;      // output channel
    float ar = 0.f, ai = 0.f;
    #pragma unroll 8
    for (int i = 0; i < 64; ++i) {           // input channel
      const float2 xv  = *(const float2*)&sxf[i * 128 + 2 * k];
      const float  wrv = wc[(size_t)i * 4096 + o * 64 + k];
      const float  wiv = wi[(size_t)i * 4096 + o * 64 + k];
      ar = fmaf(xv.x, wrv, ar);  ar = fmaf(-xv.y, wiv, ar);
      ai = fmaf(xv.x, wiv, ai);  ai = fmaf(xv.y, wrv, ai);
    }
    uint32_t* row = tf_out + ((size_t)b * 64 + o) * 96;
    row[k] = (uint32_t)f2bf(ar) | ((uint32_t)f2bf(ai) << 16);
    if (k < 32)                              // pw rows: bf16 pairs [64..96)
      row[64 + k] = (uint32_t)f2bf(pww[o * 64 + 2 * k]) |
                    ((uint32_t)f2bf(pww[o * 64 + 2 * k + 1]) << 16);
  }
}

// ---------------------------------------------------------------------------
// k3 v3 (unchanged from round 3): TF staged into LDS (rows padded 192->200
// bf16), all 8 pointwise x f32x4 loads hoisted to kernel entry.
// ---------------------------------------------------------------------------
__global__ __launch_bounds__(256) void k3_out(const float* __restrict__ x,
                                              const unsigned short* __restrict__ tf,
                                              const float* __restrict__ bias,
                                              float* __restrict__ out) {
  const int b = blockIdx.x >> 6;
  const int lt = blockIdx.x & 63;
  const int t = threadIdx.x;
  const int wv = t >> 6;
  const int lane = t & 63;
  const int q = lane >> 4;
  const int n = lane & 15;
  const int l0 = lt * 128 + wv * 32;   // wave: 32 l-cols x 64 c-rows
  const float* xb = x + (size_t)b * L_ * NC;
  const unsigned short* tfb = tf + (size_t)b * 64 * 192;
  const float W0 = 6.283185307179586f / 8192.0f;
  const int lA = l0 + n;               // l for nt=0 (B-frag col = lane n)
  const int lB = l0 + 16 + n;          // l for nt=1

  // hoist pointwise x loads (consumed at s=4,5)
  const f32x4* pA0 = (const f32x4*)(xb + (size_t)lA * NC + q * 8);
  const f32x4* pB0 = (const f32x4*)(xb + (size_t)lB * NC + q * 8);
  const f32x4* pA1 = (const f32x4*)(xb + (size_t)lA * NC + 32 + q * 8);
  const f32x4* pB1 = (const f32x4*)(xb + (size_t)lB * NC + 32 + q * 8);
  const f32x4 xA00 = pA0[0], xA01 = pA0[1];
  const f32x4 xB00 = pB0[0], xB01 = pB0[1];
  const f32x4 xA10 = pA1[0], xA11 = pA1[1];
  const f32x4 xB10 = pB1[0], xB11 = pB1[1];

  // stage TF into LDS, rows padded 192 -> 200 bf16 (25.6 KiB)
  __shared__ unsigned short stf[64 * 200];
  {
    uint4* dst = (uint4*)stf;
    const uint4* src = (const uint4*)tfb;    // 1536 uint4 = 24 KiB
    #pragma unroll
    for (int i = 0; i < 6; ++i) {
      const int e4 = t + i * 256;
      const int row = e4 / 24, c4 = e4 - row * 24;   // 24 uint4 per 192-bf16 row
      dst[row * 25 + c4] = src[e4];                  // dst row stride 25 uint4
    }
  }
  __syncthreads();

  f32x4 acc[4][2];                     // [c-tile mt][l-tile nt]
  #pragma unroll
  for (int i = 0; i < 4; ++i)
    #pragma unroll
    for (int jn = 0; jn < 2; ++jn) acc[i][jn] = (f32x4){0.f, 0.f, 0.f, 0.f};

  #pragma unroll
  for (int s = 0; s < 6; ++s) {
    const int k0 = s * 32;
    bf16x8 b0, b1;
    if (s < 4) {                       // spectral: Bi[k][l] on the fly
      #pragma unroll
      for (int jj = 0; jj < 4; ++jj) {
        const int kf = (k0 >> 1) + q * 4 + jj;
        float sv, cv;
        __sincosf((float)((kf * lA) & 8191) * W0, &sv, &cv);
        b0[2 * jj] = (__bf16)cv; b0[2 * jj + 1] = (__bf16)(-sv);
        __sincosf((float)((kf * lB) & 8191) * W0, &sv, &cv);
        b1[2 * jj] = (__bf16)cv; b1[2 * jj + 1] = (__bf16)(-sv);
      }
    } else if (s == 4) {               // pointwise: hoisted x regs
      #pragma unroll
      for (int jj = 0; jj < 4; ++jj) {
        b0[jj] = (__bf16)xA00[jj]; b0[4 + jj] = (__bf16)xA01[jj];
        b1[jj] = (__bf16)xB00[jj]; b1[4 + jj] = (__bf16)xB01[jj];
      }
    } else {
      #pragma unroll
      for (int jj = 0; jj < 4; ++jj) {
        b0[jj] = (__bf16)xA10[jj]; b0[4 + jj] = (__bf16)xA11[jj];
        b1[jj] = (__bf16)xB10[jj]; b1[4 + jj] = (__bf16)xB11[jj];
      }
    }
    #pragma unroll
    for (int mt = 0; mt < 4; ++mt) {   // A-frag: TF row mt*16+n from LDS
      const bf16x8 afr = *(const bf16x8*)(stf + (mt * 16 + n) * 200 + k0 + q * 8);
      acc[mt][0] = mfma16(afr, b0, acc[mt][0]);
      acc[mt][1] = mfma16(afr, b1, acc[mt][1]);
    }
  }
  float* ob = out + (size_t)b * L_ * NC;
  #pragma unroll
  for (int mt = 0; mt < 4; ++mt) {
    const f32x4 bv = *(const f32x4*)(bias + mt * 16 + q * 4);
    #pragma unroll
    for (int nt = 0; nt < 2; ++nt) {
      const int l = l0 + nt * 16 + n;
      f32x4 v = acc[mt][nt];
      v[0] += bv[0]; v[1] += bv[1]; v[2] += bv[2]; v[3] += bv[3];
      *(f32x4*)(ob + (size_t)l * NC + mt * 16 + q * 4) = v;
    }
  }
}

// ---------------------------------------------------------------------------
extern "C" void kernel_launch(void* const* d_in, const int* in_sizes, int n_in,
                              void* d_out, int out_size, void* d_ws, size_t ws_size,
                              hipStream_t stream) {
  (void)in_sizes; (void)n_in; (void)out_size; (void)d_ws; (void)ws_size;
  const float* x    = (const float*)d_in[0];
  float*       wr   = (float*)d_in[1];        // dead after k0 copy -> TF home
  const float* wi   = (const float*)d_in[2];
  const float* pww  = (const float*)d_in[3];
  const float* bias = (const float*)d_in[4];
  float* out = (float*)d_out;

  char* ob = (char*)d_out;
  unsigned short* Bf  = (unsigned short*)(ob + BF_OFF);
  float*          XFP = (float*)(ob + XF_OFF);
  float*          XFR = (float*)(ob + XR_OFF);
  float*          WC  = (float*)(ob + WC_OFF);

  k0_bf   <<<512,         256, 0, stream>>>(Bf, (const uint2*)wr, (uint2*)WC);
  k1_dft  <<<NB * SPLITK, 256, 0, stream>>>(x, Bf, XFP);
  k1b_red <<<256,         256, 0, stream>>>((const f32x4*)XFP, (f32x4*)XFR);
  k2_mix  <<<NB * 8,      256, 0, stream>>>(XFR, WC, wi, pww, (uint32_t*)wr);
  k3_out  <<<NB * 64,     256, 0, stream>>>(x, (const unsigned short*)wr, bias, out);
}